// Round 11
// baseline (209.825 us; speedup 1.0000x reference)
//
#include <hip/hip_runtime.h>

#define MD 8192
#define ND 8192
#define DD 256
#define KTOP 256
#define CAND_T0 0.26f
#define NCAP 4096
#define NPAD 4096

typedef unsigned int u32;
typedef unsigned short u16;
typedef unsigned long long u64;

// workspace layout (bytes)
#define OFF_R    0                  // double R[8192]          64 KB
#define OFF_CP   65536              // double CP[8][8192]     512 KB
#define OFF_CNT  589824             // int
#define OFF_CAND 589952             // u32 cand[4096]          16 KB
#define OFF_KEYS 606336             // u64 keys[4096]          32 KB
#define OFF_AH   655360             // u16 Ah[8192*256]         4 MB
#define OFF_AL   (OFF_AH + 4194304)
#define OFF_BH   (OFF_AL + 4194304)
#define OFF_BL   (OFF_BH + 4194304)
#define WS_REQ   (OFF_BL + 4194304)

using bf16x8 = __attribute__((ext_vector_type(8))) __bf16;
using f32x4  = __attribute__((ext_vector_type(4))) float;
using f32x16 = __attribute__((ext_vector_type(16))) float;

#define AS1 __attribute__((address_space(1)))
#define AS3 __attribute__((address_space(3)))

__device__ __forceinline__ u16 f2bf(float x) {
  union { float f; u32 u; } v; v.f = x;
  u32 r = v.u + 0x7fffu + ((v.u >> 16) & 1u);   // RNE
  return (u16)(r >> 16);
}
__device__ __forceinline__ float bf2f(u16 h) {
  union { float f; u32 u; } v; v.u = ((u32)h) << 16;
  return v.f;
}

// fallback-path init: zero R, CP, cnt (grid-stride)
__global__ void k_init(double* __restrict__ R, double* __restrict__ CP, int* __restrict__ cnt) {
  int stride = gridDim.x * blockDim.x;
  for (int i = blockIdx.x * blockDim.x + threadIdx.x; i < MD + 8 * ND; i += stride) {
    if (i < MD) R[i] = 0.0;
    else CP[i - MD] = 0.0;
  }
  if (blockIdx.x == 0 && threadIdx.x == 0) *cnt = 0;
}

// Fused: zero R/CP/cnt + split BOTH matrices into (hi, lo) bf16 planes.
__global__ __launch_bounds__(256) void k_prep2(
    const float* __restrict__ A, const float* __restrict__ B,
    u16* __restrict__ Ahp, u16* __restrict__ Alp,
    u16* __restrict__ Bhp, u16* __restrict__ Blp,
    double* __restrict__ R, double* __restrict__ CP, int* __restrict__ cnt) {
  const int gid = blockIdx.x * 256 + threadIdx.x;
  if (gid < MD) R[gid] = 0.0;
  if (gid < 8 * ND) CP[gid] = 0.0;
  if (gid == 0) *cnt = 0;

  {
    float4 v = ((const float4*)A)[gid];
    ushort4 h, l;
    h.x = f2bf(v.x); l.x = f2bf(v.x - bf2f(h.x));
    h.y = f2bf(v.y); l.y = f2bf(v.y - bf2f(h.y));
    h.z = f2bf(v.z); l.z = f2bf(v.z - bf2f(h.z));
    h.w = f2bf(v.w); l.w = f2bf(v.w - bf2f(h.w));
    ((ushort4*)Ahp)[gid] = h;
    ((ushort4*)Alp)[gid] = l;
  }
  {
    float4 v = ((const float4*)B)[gid];
    ushort4 h, l;
    h.x = f2bf(v.x); l.x = f2bf(v.x - bf2f(h.x));
    h.y = f2bf(v.y); l.y = f2bf(v.y - bf2f(h.y));
    h.z = f2bf(v.z); l.z = f2bf(v.z - bf2f(h.z));
    h.w = f2bf(v.w); l.w = f2bf(v.w - bf2f(h.w));
    ((ushort4*)Bhp)[gid] = h;
    ((ushort4*)Blp)[gid] = l;
  }
}

// ---------------- MFMA split-bf16 GEMM, 32x32x16 shape ----------------
// 128x128 tile, BK=32, 4 waves each 64x64 = 2x2 tiles of 32x32.
// c = ah*bh + ah*bl + al*bh, fp32 MFMA accumulate (layouts validated R4).
// 24 MFMA x 8.07cyc = 192 cyc/kt vs 48 x 4.85 = 233 for 16x16 (m119).
// XOR chunk swizzle: lane reads chunk (2h+hi1)^((lo5>>1)&3) -> 8 lanes/
// bank-quad = throughput minimum, conflict-free. (256,3): no spill (R9/R10).
__global__ __launch_bounds__(256, 3) void k_gemm_mfma(
    const u16* __restrict__ Ah, const u16* __restrict__ Al,
    const u16* __restrict__ Bh, const u16* __restrict__ Bl,
    double* __restrict__ R, double* __restrict__ CP,
    int* __restrict__ cnt, u32* __restrict__ cand, int ncap) {
  __shared__ u16 sAh[128][32];
  __shared__ u16 sAl[128][32];
  __shared__ u16 sBh[128][32];
  __shared__ u16 sBl[128][32];
  __shared__ float sR[2][64];      // [wrow][row 0..63]  from wcol==1
  __shared__ double sC[2][64];     // [wcol][col 0..63]  from wrow==1

  const int tid = threadIdx.x;
  const int lane = tid & 63;
  const int wid = tid >> 6;           // 0..3
  const int wrow = wid >> 1, wcol = wid & 1;

  // XCD-aware block swizzle (1-D grid of 4096)
  const int g = blockIdx.x;
  const int xcd = g & 7;
  const int l = g >> 3;               // 0..511
  const int rowTile = xcd * 8 + (l & 7);
  const int colTile = l >> 3;
  const int rowBase = rowTile * 128;
  const int colBase = colTile * 128;
  double* Cmy = CP + (size_t)xcd * ND;

  const int lo5 = lane & 31, hi1 = lane >> 5;
  const int sw = (lo5 >> 1) & 3;
  const int cswz = (lane & 3) ^ ((lane >> 3) & 3);

  u16* lb;
  const u16* gb;
  if (wid == 0)      { lb = &sAh[0][0]; gb = Ah + (size_t)rowBase * DD; }
  else if (wid == 1) { lb = &sAl[0][0]; gb = Al + (size_t)rowBase * DD; }
  else if (wid == 2) { lb = &sBh[0][0]; gb = Bh + (size_t)colBase * DD; }
  else               { lb = &sBl[0][0]; gb = Bl + (size_t)colBase * DD; }

  f32x16 acc[2][2];
#pragma unroll
  for (int i = 0; i < 2; ++i)
#pragma unroll
    for (int j = 0; j < 2; ++j)
#pragma unroll
      for (int r = 0; r < 16; ++r) acc[i][j][r] = 0.f;

  for (int kt = 0; kt < 8; ++kt) {
    const int kk = kt * 32;
#pragma unroll
    for (int ch = 0; ch < 8; ++ch) {
      const u16* gp = gb + (size_t)(ch * 16 + (lane >> 2)) * DD + kk + cswz * 8;
      __builtin_amdgcn_global_load_lds((const AS1 void*)gp, (AS3 void*)(lb + ch * 512), 16, 0, 0);
    }
    __syncthreads();

    // A fragments: A[m=lo5][k = h*16 + hi1*8 + j]  (validated R4)
    bf16x8 fah[2][2], fal[2][2];   // [tile i][k-half h]
#pragma unroll
    for (int i = 0; i < 2; ++i)
#pragma unroll
      for (int h = 0; h < 2; ++h) {
        const int cq = (((h << 1) + hi1) ^ sw) * 8;
        fah[i][h] = *(const bf16x8*)&sAh[wrow * 64 + i * 32 + lo5][cq];
        fal[i][h] = *(const bf16x8*)&sAl[wrow * 64 + i * 32 + lo5][cq];
      }
#pragma unroll
    for (int j = 0; j < 2; ++j) {
      bf16x8 fbh[2], fbl[2];
#pragma unroll
      for (int h = 0; h < 2; ++h) {
        const int cq = (((h << 1) + hi1) ^ sw) * 8;
        fbh[h] = *(const bf16x8*)&sBh[wcol * 64 + j * 32 + lo5][cq];
        fbl[h] = *(const bf16x8*)&sBl[wcol * 64 + j * 32 + lo5][cq];
      }
#pragma unroll
      for (int i = 0; i < 2; ++i)
#pragma unroll
        for (int h = 0; h < 2; ++h) {
          acc[i][j] = __builtin_amdgcn_mfma_f32_32x32x16_bf16(fah[i][h], fbh[h], acc[i][j], 0, 0, 0);
          acc[i][j] = __builtin_amdgcn_mfma_f32_32x32x16_bf16(fah[i][h], fbl[h], acc[i][j], 0, 0, 0);
          acc[i][j] = __builtin_amdgcn_mfma_f32_32x32x16_bf16(fal[i][h], fbh[h], acc[i][j], 0, 0, 0);
        }
    }
    __syncthreads();
  }

  // epilogue: e = exp(2c-2); row partials fp32, col partials fp64; candidates.
  // C/D layout (m74/m101): col = lo5, row = (r&3) + 8*(r>>2) + 4*hi1
  float rowp[2][16];
  double colp[2];
#pragma unroll
  for (int i = 0; i < 2; ++i)
#pragma unroll
    for (int r = 0; r < 16; ++r) rowp[i][r] = 0.f;
#pragma unroll
  for (int j = 0; j < 2; ++j) colp[j] = 0.0;

#pragma unroll
  for (int i = 0; i < 2; ++i)
#pragma unroll
    for (int j = 0; j < 2; ++j)
#pragma unroll
      for (int r = 0; r < 16; ++r) {
        float c = acc[i][j][r];
        float e = __expf(2.f * c - 2.f);
        rowp[i][r] += e;
        colp[j] += (double)e;
        if (c >= CAND_T0) {
          int row = rowBase + wrow * 64 + i * 32 + (r & 3) + 8 * (r >> 2) + 4 * hi1;
          int col = colBase + wcol * 64 + j * 32 + lo5;
          int idx = atomicAdd(cnt, 1);
          if (idx < ncap) cand[idx] = ((u32)row << 13) | (u32)col;
        }
      }

  // reduce rowp over the 32 lo5-lanes (width-32 butterfly)
#pragma unroll
  for (int i = 0; i < 2; ++i)
#pragma unroll
    for (int r = 0; r < 16; ++r) {
      float v = rowp[i][r];
#pragma unroll
      for (int off = 16; off; off >>= 1) v += __shfl_xor(v, off, 32);
      rowp[i][r] = v;
    }
  // reduce colp over the 2 hi1 halves
#pragma unroll
  for (int j = 0; j < 2; ++j) colp[j] += __shfl_xor(colp[j], 32);

  // cross-wave combine: wcol==1 -> sR, wrow==1 -> sC
  if (wcol == 1 && lo5 == 0) {
#pragma unroll
    for (int i = 0; i < 2; ++i)
#pragma unroll
      for (int r = 0; r < 16; ++r)
        sR[wrow][i * 32 + (r & 3) + 8 * (r >> 2) + 4 * hi1] = rowp[i][r];
  }
  if (wrow == 1 && hi1 == 0) {
#pragma unroll
    for (int j = 0; j < 2; ++j) sC[wcol][j * 32 + lo5] = colp[j];
  }
  __syncthreads();

  if (wcol == 0 && lo5 == 0) {
#pragma unroll
    for (int i = 0; i < 2; ++i)
#pragma unroll
      for (int r = 0; r < 16; ++r) {
        int idx = i * 32 + (r & 3) + 8 * (r >> 2) + 4 * hi1;
        atomicAdd(&R[rowBase + wrow * 64 + idx], (double)(rowp[i][r] + sR[wrow][idx]));
      }
  }
  if (wrow == 0 && hi1 == 0) {
#pragma unroll
    for (int j = 0; j < 2; ++j) {
      int idx = j * 32 + lo5;
      atomicAdd(&Cmy[colBase + wcol * 64 + idx], colp[j] + sC[wcol][idx]);
    }
  }
}

// ---------------- fp32 fallback GEMM (used only if ws too small) ----------------
__global__ __launch_bounds__(256) void k_gemm_f32(
    const float* __restrict__ A, const float* __restrict__ B,
    double* __restrict__ R, double* __restrict__ CP,
    int* __restrict__ cnt, u32* __restrict__ cand, int ncap) {
  __shared__ float As[32][128];
  __shared__ float Bs[32][128];
  __shared__ double colLds[16][128];
  const int tid = threadIdx.x;
  const int tx = tid & 15, ty = tid >> 4;
  const int rowBase = blockIdx.y * 128;
  const int colBase = blockIdx.x * 128;
  float acc[8][8];
#pragma unroll
  for (int i = 0; i < 8; ++i)
#pragma unroll
    for (int j = 0; j < 8; ++j) acc[i][j] = 0.f;
  const int lr = tid >> 3;
  const int lc = (tid & 7) << 2;
  for (int kk = 0; kk < DD; kk += 32) {
#pragma unroll
    for (int r = 0; r < 4; ++r) {
      int row = lr + r * 32;
      float4 av = *(const float4*)(A + (size_t)(rowBase + row) * DD + kk + lc);
      float4 bv = *(const float4*)(B + (size_t)(colBase + row) * DD + kk + lc);
      As[lc + 0][row] = av.x; As[lc + 1][row] = av.y; As[lc + 2][row] = av.z; As[lc + 3][row] = av.w;
      Bs[lc + 0][row] = bv.x; Bs[lc + 1][row] = bv.y; Bs[lc + 2][row] = bv.z; Bs[lc + 3][row] = bv.w;
    }
    __syncthreads();
#pragma unroll 4
    for (int k = 0; k < 32; ++k) {
      float a[8], b[8];
      *(float4*)(a + 0) = *(const float4*)(&As[k][ty * 8 + 0]);
      *(float4*)(a + 4) = *(const float4*)(&As[k][ty * 8 + 4]);
      *(float4*)(b + 0) = *(const float4*)(&Bs[k][tx * 8 + 0]);
      *(float4*)(b + 4) = *(const float4*)(&Bs[k][tx * 8 + 4]);
#pragma unroll
      for (int i = 0; i < 8; ++i)
#pragma unroll
        for (int j = 0; j < 8; ++j)
          acc[i][j] = fmaf(a[i], b[j], acc[i][j]);
    }
    __syncthreads();
  }
  double colpart[8];
#pragma unroll
  for (int j = 0; j < 8; ++j) colpart[j] = 0.0;
#pragma unroll
  for (int i = 0; i < 8; ++i) {
    double rp = 0.0;
#pragma unroll
    for (int j = 0; j < 8; ++j) {
      float e = __expf(2.f * acc[i][j] - 2.f);
      rp += (double)e;
      colpart[j] += (double)e;
    }
#pragma unroll
    for (int off = 8; off; off >>= 1) rp += __shfl_down(rp, off, 16);
    if (tx == 0) atomicAdd(&R[rowBase + ty * 8 + i], rp);
  }
#pragma unroll
  for (int j = 0; j < 8; ++j) colLds[ty][tx * 8 + j] = colpart[j];
  __syncthreads();
  if (tid < 128) {
    double s = 0.0;
#pragma unroll
    for (int t = 0; t < 16; ++t) s += colLds[t][tid];
    atomicAdd(&CP[colBase + tid], s);   // partition 0 only
  }
#pragma unroll
  for (int i = 0; i < 8; ++i)
#pragma unroll
    for (int j = 0; j < 8; ++j) {
      if (acc[i][j] >= CAND_T0) {
        int idx = atomicAdd(cnt, 1);
        if (idx < ncap)
          cand[idx] = ((u32)(rowBase + ty * 8 + i) << 13) | (u32)(colBase + tx * 8 + j);
      }
    }
}

// One wave per candidate: exact fp64 dot, fp64 score, orderable u64 key.
__global__ __launch_bounds__(256) void k_score(
    const float* __restrict__ A, const float* __restrict__ B,
    const double* __restrict__ R, const double* __restrict__ CP,
    const int* __restrict__ cnt, const u32* __restrict__ cand,
    u64* __restrict__ keys, int ncap) {
  int w = (int)((blockIdx.x * 256 + threadIdx.x) >> 6);
  int lane = threadIdx.x & 63;
  int n = *cnt; if (n > ncap) n = ncap;
  if (w >= n) return;
  u32 mn = cand[w];
  int m = (int)(mn >> 13), nn = (int)(mn & 8191u);
  const float* ar = A + (size_t)m * DD;
  const float* br = B + (size_t)nn * DD;
  double s = 0.0;
#pragma unroll
  for (int d = 0; d < DD; d += 64)
    s = fma((double)ar[d + lane], (double)br[d + lane], s);
#pragma unroll
  for (int off = 32; off; off >>= 1) s += __shfl_down(s, off);
  if (lane == 0) {
    double Cn = 0.0;
#pragma unroll
    for (int x = 0; x < 8; ++x) Cn += CP[(size_t)x * ND + nn];
    double sc = exp(4.0 * s - 4.0) / (R[m] * Cn);
    keys[w] = (u64)__double_as_longlong(sc);
  }
}

// (key desc, flat-idx asc) strict order; idx unique so no true ties.
__device__ __forceinline__ bool is_worse(u64 ka, u32 ma, u64 kb, u32 mb) {
  return (ka < kb) || (ka == kb && ma > mb);
}

// Single-block top-256: register/shuffle bitonic (fast path n<=2048),
// legacy 4096 LDS bitonic fallback.
__global__ __launch_bounds__(1024) void k_sort(
    const int* __restrict__ cnt, const u32* __restrict__ cand,
    const u64* __restrict__ keys, float* __restrict__ out, int ncap) {
  __shared__ u64 sk[NPAD];
  __shared__ u32 sm[NPAD];
  const int tid = threadIdx.x;
  const int lane = tid & 63;
  const int wid = tid >> 6;
  int m = *cnt; if (m > ncap) m = ncap;

  if (m <= 2048) {
    const int NP = 2048;
    const int base = wid * 128;
    const int i0 = base + lane * 2;

    u64 k0 = (i0 < m) ? keys[i0] : 0;
    u64 k1 = (i0 + 1 < m) ? keys[i0 + 1] : 0;
    u32 m0 = (i0 < m) ? cand[i0] : 0xFFFFFFFFu;
    u32 m1 = (i0 + 1 < m) ? cand[i0 + 1] : 0xFFFFFFFFu;
#pragma unroll
    for (int k = 2; k <= 128; k <<= 1) {
#pragma unroll
      for (int j = k >> 1; j >= 1; j >>= 1) {
        const bool bf = ((i0 & k) == 0);
        if (j == 1) {
          bool sw = bf ? is_worse(k0, m0, k1, m1) : is_worse(k1, m1, k0, m0);
          if (sw) { u64 tk = k0; k0 = k1; k1 = tk; u32 tm = m0; m0 = m1; m1 = tm; }
        } else {
          const int j2 = j >> 1;
          const bool keepb = (bf == ((lane & j2) == 0));
          u64 pk0 = __shfl_xor(k0, j2); u32 pm0 = __shfl_xor(m0, j2);
          u64 pk1 = __shfl_xor(k1, j2); u32 pm1 = __shfl_xor(m1, j2);
          if (keepb == is_worse(k0, m0, pk0, pm0)) { k0 = pk0; m0 = pm0; }
          if (keepb == is_worse(k1, m1, pk1, pm1)) { k1 = pk1; m1 = pm1; }
        }
      }
    }
    sk[i0] = k0; sk[i0 + 1] = k1; sm[i0] = m0; sm[i0 + 1] = m1;
    __syncthreads();

    for (int k = 256; k <= NP; k <<= 1) {
      for (int j = k >> 1; j >= 128; j >>= 1) {
        for (int i = tid; i < NP; i += 1024) {
          int l = i ^ j;
          if (l > i) {
            u64 ki = sk[i], kl = sk[l];
            u32 mi = sm[i], ml = sm[l];
            bool bf = ((i & k) == 0);
            bool swp = bf ? is_worse(ki, mi, kl, ml) : is_worse(kl, ml, ki, mi);
            if (swp) { sk[i] = kl; sk[l] = ki; sm[i] = ml; sm[l] = mi; }
          }
        }
        __syncthreads();
      }
      k0 = sk[i0]; k1 = sk[i0 + 1]; m0 = sm[i0]; m1 = sm[i0 + 1];
      const bool bf = ((base & k) == 0);
#pragma unroll
      for (int j = 64; j >= 2; j >>= 1) {
        const int j2 = j >> 1;
        const bool keepb = (bf == ((lane & j2) == 0));
        u64 pk0 = __shfl_xor(k0, j2); u32 pm0 = __shfl_xor(m0, j2);
        u64 pk1 = __shfl_xor(k1, j2); u32 pm1 = __shfl_xor(m1, j2);
        if (keepb == is_worse(k0, m0, pk0, pm0)) { k0 = pk0; m0 = pm0; }
        if (keepb == is_worse(k1, m1, pk1, pm1)) { k1 = pk1; m1 = pm1; }
      }
      {
        bool sw = bf ? is_worse(k0, m0, k1, m1) : is_worse(k1, m1, k0, m0);
        if (sw) { u64 tk = k0; k0 = k1; k1 = tk; u32 tm = m0; m0 = m1; m1 = tm; }
      }
      __syncthreads();
      sk[i0] = k0; sk[i0 + 1] = k1; sm[i0] = m0; sm[i0 + 1] = m1;
      __syncthreads();
    }
  } else {
    for (int i = tid; i < NPAD; i += 1024) { sk[i] = 0; sm[i] = 0xFFFFFFFFu; }
    __syncthreads();
    for (int i = tid; i < m; i += 1024) { sk[i] = keys[i]; sm[i] = cand[i]; }
    __syncthreads();
    for (unsigned k = 2; k <= (unsigned)NPAD; k <<= 1) {
      for (unsigned j = k >> 1; j > 0; j >>= 1) {
        for (unsigned i = tid; i < (unsigned)NPAD; i += 1024) {
          unsigned l = i ^ j;
          if (l > i) {
            u64 ki = sk[i], kl = sk[l];
            u32 mi = sm[i], ml = sm[l];
            bool dir = ((i & k) == 0);
            bool swp = dir ? is_worse(ki, mi, kl, ml) : is_worse(kl, ml, ki, mi);
            if (swp) { sk[i] = kl; sk[l] = ki; sm[i] = ml; sm[l] = mi; }
          }
        }
        __syncthreads();
      }
    }
  }

  for (int r = tid; r < KTOP; r += 1024) {
    u32 mn = sm[r];
    u64 kk = sk[r];
    out[r] = (float)(mn >> 13);
    out[KTOP + r] = (float)(mn & 8191u);
    out[2 * KTOP + r] = (float)__longlong_as_double((long long)kk);
  }
}

extern "C" void kernel_launch(void* const* d_in, const int* in_sizes, int n_in,
                              void* d_out, int out_size, void* d_ws, size_t ws_size,
                              hipStream_t stream) {
  (void)in_sizes; (void)n_in; (void)out_size;
  const float* A = (const float*)d_in[0];  // ref_feats [8192,256]
  const float* B = (const float*)d_in[1];  // src_feats [8192,256]
  float* out = (float*)d_out;
  char* ws = (char*)d_ws;
  double* R = (double*)(ws + OFF_R);
  double* CP = (double*)(ws + OFF_CP);
  int* cnt = (int*)(ws + OFF_CNT);
  u32* cand = (u32*)(ws + OFF_CAND);
  u64* keys = (u64*)(ws + OFF_KEYS);

  if (ws_size >= (size_t)WS_REQ) {
    u16* Ahp = (u16*)(ws + OFF_AH);
    u16* Alp = (u16*)(ws + OFF_AL);
    u16* Bhp = (u16*)(ws + OFF_BH);
    u16* Blp = (u16*)(ws + OFF_BL);
    hipLaunchKernelGGL(k_prep2, dim3(2048), dim3(256), 0, stream,
                       A, B, Ahp, Alp, Bhp, Blp, R, CP, cnt);
    hipLaunchKernelGGL(k_gemm_mfma, dim3(4096), dim3(256), 0, stream,
                       Ahp, Alp, Bhp, Blp, R, CP, cnt, cand, NCAP);
  } else {
    hipLaunchKernelGGL(k_init, dim3(288), dim3(256), 0, stream, R, CP, cnt);
    hipLaunchKernelGGL(k_gemm_f32, dim3(ND / 128, MD / 128), dim3(256), 0, stream,
                       A, B, R, CP, cnt, cand, NCAP);
  }

  hipLaunchKernelGGL(k_score, dim3(NCAP / 4), dim3(256), 0, stream,
                     A, B, R, CP, cnt, cand, keys, NCAP);
  hipLaunchKernelGGL(k_sort, dim3(1), dim3(1024), 0, stream,
                     cnt, cand, keys, out, NCAP);
}

// Round 12
// 186.161 us; speedup vs baseline: 1.1271x; 1.1271x over previous
//
#include <hip/hip_runtime.h>

#define MD 8192
#define ND 8192
#define DD 256
#define KTOP 256
#define CAND_T0 0.26f
#define NCAP 4096
#define NPAD 4096

typedef unsigned int u32;
typedef unsigned short u16;
typedef unsigned long long u64;

// workspace layout (bytes)
#define OFF_R    0                  // double R[8192]          64 KB
#define OFF_CP   65536              // double CP[8][8192]     512 KB
#define OFF_CNT  589824             // int
#define OFF_CAND 589952             // u32 cand[4096]          16 KB
#define OFF_KEYS 606336             // u64 keys[4096]          32 KB
#define OFF_AH   655360             // u16 Ah[8192*256]         4 MB
#define OFF_AL   (OFF_AH + 4194304)
#define OFF_BH   (OFF_AL + 4194304)
#define OFF_BL   (OFF_BH + 4194304)
#define WS_REQ   (OFF_BL + 4194304)

using bf16x8 = __attribute__((ext_vector_type(8))) __bf16;
using f32x4  = __attribute__((ext_vector_type(4))) float;

#define AS1 __attribute__((address_space(1)))
#define AS3 __attribute__((address_space(3)))

__device__ __forceinline__ u16 f2bf(float x) {
  union { float f; u32 u; } v; v.f = x;
  u32 r = v.u + 0x7fffu + ((v.u >> 16) & 1u);   // RNE
  return (u16)(r >> 16);
}
__device__ __forceinline__ float bf2f(u16 h) {
  union { float f; u32 u; } v; v.u = ((u32)h) << 16;
  return v.f;
}

// fallback-path init: zero R, CP, cnt (grid-stride)
__global__ void k_init(double* __restrict__ R, double* __restrict__ CP, int* __restrict__ cnt) {
  int stride = gridDim.x * blockDim.x;
  for (int i = blockIdx.x * blockDim.x + threadIdx.x; i < MD + 8 * ND; i += stride) {
    if (i < MD) R[i] = 0.0;
    else CP[i - MD] = 0.0;
  }
  if (blockIdx.x == 0 && threadIdx.x == 0) *cnt = 0;
}

// Fused: zero R/CP/cnt + split BOTH matrices into (hi, lo) bf16 planes.
__global__ __launch_bounds__(256) void k_prep2(
    const float* __restrict__ A, const float* __restrict__ B,
    u16* __restrict__ Ahp, u16* __restrict__ Alp,
    u16* __restrict__ Bhp, u16* __restrict__ Blp,
    double* __restrict__ R, double* __restrict__ CP, int* __restrict__ cnt) {
  const int gid = blockIdx.x * 256 + threadIdx.x;
  if (gid < MD) R[gid] = 0.0;
  if (gid < 8 * ND) CP[gid] = 0.0;
  if (gid == 0) *cnt = 0;

  {
    float4 v = ((const float4*)A)[gid];
    ushort4 h, l;
    h.x = f2bf(v.x); l.x = f2bf(v.x - bf2f(h.x));
    h.y = f2bf(v.y); l.y = f2bf(v.y - bf2f(h.y));
    h.z = f2bf(v.z); l.z = f2bf(v.z - bf2f(h.z));
    h.w = f2bf(v.w); l.w = f2bf(v.w - bf2f(h.w));
    ((ushort4*)Ahp)[gid] = h;
    ((ushort4*)Alp)[gid] = l;
  }
  {
    float4 v = ((const float4*)B)[gid];
    ushort4 h, l;
    h.x = f2bf(v.x); l.x = f2bf(v.x - bf2f(h.x));
    h.y = f2bf(v.y); l.y = f2bf(v.y - bf2f(h.y));
    h.z = f2bf(v.z); l.z = f2bf(v.z - bf2f(h.z));
    h.w = f2bf(v.w); l.w = f2bf(v.w - bf2f(h.w));
    ((ushort4*)Bhp)[gid] = h;
    ((ushort4*)Blp)[gid] = l;
  }
}

// ---------------- MFMA split-bf16 GEMM (R9 configuration — best measured) ----
// 128x128 tile, BK=32, 4 waves each 64x64 (4x4 tiles of 16x16x32).
// c = ah*bh + ah*bl + al*bh, fp32 MFMA accumulate.
// XOR chunk swizzle: conflict-free (R5/R9: SQ_LDS_BANK_CONFLICT = 0).
// 32x32x16 shape tried twice (R4, R11): loses to shape-specific LDS
// conflicts (8.4e6) — do not revisit without a µarch phase model.
// (256,3): no spill (R10 proved (256,4) spills ~94MB). Cross-wave LDS
// combine halves device-scope atomics (WRITE 41 -> 20.5 MB).
__global__ __launch_bounds__(256, 3) void k_gemm_mfma(
    const u16* __restrict__ Ah, const u16* __restrict__ Al,
    const u16* __restrict__ Bh, const u16* __restrict__ Bl,
    double* __restrict__ R, double* __restrict__ CP,
    int* __restrict__ cnt, u32* __restrict__ cand, int ncap) {
  __shared__ u16 sAh[128][32];
  __shared__ u16 sAl[128][32];
  __shared__ u16 sBh[128][32];
  __shared__ u16 sBl[128][32];
  __shared__ float sR[2][64];      // [wrow][i*16+quad*4+r]  from wcol==1
  __shared__ double sC[2][64];     // [wcol][j*16+lo]        from wrow==1

  const int tid = threadIdx.x;
  const int lane = tid & 63;
  const int wid = tid >> 6;           // 0..3
  const int wrow = wid >> 1, wcol = wid & 1;

  // XCD-aware block swizzle (1-D grid of 4096)
  const int g = blockIdx.x;
  const int xcd = g & 7;
  const int l = g >> 3;               // 0..511
  const int rowTile = xcd * 8 + (l & 7);
  const int colTile = l >> 3;
  const int rowBase = rowTile * 128;
  const int colBase = colTile * 128;
  double* Cmy = CP + (size_t)xcd * ND;

  const int quad = lane >> 4, lo = lane & 15;
  const int sw = (lo >> 1) & 3;
  const int cswz = (lane & 3) ^ ((lane >> 3) & 3);

  u16* lb;
  const u16* gb;
  if (wid == 0)      { lb = &sAh[0][0]; gb = Ah + (size_t)rowBase * DD; }
  else if (wid == 1) { lb = &sAl[0][0]; gb = Al + (size_t)rowBase * DD; }
  else if (wid == 2) { lb = &sBh[0][0]; gb = Bh + (size_t)colBase * DD; }
  else               { lb = &sBl[0][0]; gb = Bl + (size_t)colBase * DD; }

  f32x4 acc[4][4];
#pragma unroll
  for (int i = 0; i < 4; ++i)
#pragma unroll
    for (int j = 0; j < 4; ++j) acc[i][j] = (f32x4){0.f, 0.f, 0.f, 0.f};

  for (int kt = 0; kt < 8; ++kt) {
    const int kk = kt * 32;
#pragma unroll
    for (int ch = 0; ch < 8; ++ch) {
      const u16* gp = gb + (size_t)(ch * 16 + (lane >> 2)) * DD + kk + cswz * 8;
      __builtin_amdgcn_global_load_lds((const AS1 void*)gp, (AS3 void*)(lb + ch * 512), 16, 0, 0);
    }
    __syncthreads();

    const int cq = (quad ^ sw) * 8;
    bf16x8 fah[4], fal[4];
#pragma unroll
    for (int t = 0; t < 4; ++t) {
      fah[t] = *(const bf16x8*)&sAh[wrow * 64 + t * 16 + lo][cq];
      fal[t] = *(const bf16x8*)&sAl[wrow * 64 + t * 16 + lo][cq];
    }
#pragma unroll
    for (int j = 0; j < 4; ++j) {
      bf16x8 fbh = *(const bf16x8*)&sBh[wcol * 64 + j * 16 + lo][cq];
      bf16x8 fbl = *(const bf16x8*)&sBl[wcol * 64 + j * 16 + lo][cq];
#pragma unroll
      for (int i = 0; i < 4; ++i) {
        acc[i][j] = __builtin_amdgcn_mfma_f32_16x16x32_bf16(fah[i], fbh, acc[i][j], 0, 0, 0);
        acc[i][j] = __builtin_amdgcn_mfma_f32_16x16x32_bf16(fah[i], fbl, acc[i][j], 0, 0, 0);
        acc[i][j] = __builtin_amdgcn_mfma_f32_16x16x32_bf16(fal[i], fbh, acc[i][j], 0, 0, 0);
      }
    }
    __syncthreads();
  }

  // epilogue: e = exp(2c-2); row partials fp32, col partials fp64; candidates.
  // C/D layout: col = lo, row = quad*4 + reg  (m89/m91)
  float rowp[4][4];
  double colp[4];
#pragma unroll
  for (int i = 0; i < 4; ++i)
#pragma unroll
    for (int r = 0; r < 4; ++r) rowp[i][r] = 0.f;
#pragma unroll
  for (int j = 0; j < 4; ++j) colp[j] = 0.0;

#pragma unroll
  for (int i = 0; i < 4; ++i)
#pragma unroll
    for (int j = 0; j < 4; ++j)
#pragma unroll
      for (int r = 0; r < 4; ++r) {
        float c = acc[i][j][r];
        float e = __expf(2.f * c - 2.f);
        rowp[i][r] += e;
        colp[j] += (double)e;
        if (c >= CAND_T0) {
          int row = rowBase + wrow * 64 + i * 16 + quad * 4 + r;
          int col = colBase + wcol * 64 + j * 16 + lo;
          int idx = atomicAdd(cnt, 1);
          if (idx < ncap) cand[idx] = ((u32)row << 13) | (u32)col;
        }
      }

#pragma unroll
  for (int i = 0; i < 4; ++i)
#pragma unroll
    for (int r = 0; r < 4; ++r) {
      float v = rowp[i][r];
#pragma unroll
      for (int off = 8; off; off >>= 1) v += __shfl_xor(v, off, 16);
      rowp[i][r] = v;
    }
#pragma unroll
  for (int j = 0; j < 4; ++j) {
    double v = colp[j];
    v += __shfl_xor(v, 16);
    v += __shfl_xor(v, 32);
    colp[j] = v;
  }

  if (wcol == 1 && lo == 0) {
#pragma unroll
    for (int i = 0; i < 4; ++i)
#pragma unroll
      for (int r = 0; r < 4; ++r) sR[wrow][i * 16 + quad * 4 + r] = rowp[i][r];
  }
  if (wrow == 1 && quad == 0) {
#pragma unroll
    for (int j = 0; j < 4; ++j) sC[wcol][j * 16 + lo] = colp[j];
  }
  __syncthreads();

  if (wcol == 0 && lo == 0) {
#pragma unroll
    for (int i = 0; i < 4; ++i)
#pragma unroll
      for (int r = 0; r < 4; ++r) {
        int idx = i * 16 + quad * 4 + r;
        atomicAdd(&R[rowBase + wrow * 64 + idx], (double)(rowp[i][r] + sR[wrow][idx]));
      }
  }
  if (wrow == 0 && quad == 0) {
#pragma unroll
    for (int j = 0; j < 4; ++j) {
      int idx = j * 16 + lo;
      atomicAdd(&Cmy[colBase + wcol * 64 + idx], colp[j] + sC[wcol][idx]);
    }
  }
}

// ---------------- fp32 fallback GEMM (used only if ws too small) ----------------
__global__ __launch_bounds__(256) void k_gemm_f32(
    const float* __restrict__ A, const float* __restrict__ B,
    double* __restrict__ R, double* __restrict__ CP,
    int* __restrict__ cnt, u32* __restrict__ cand, int ncap) {
  __shared__ float As[32][128];
  __shared__ float Bs[32][128];
  __shared__ double colLds[16][128];
  const int tid = threadIdx.x;
  const int tx = tid & 15, ty = tid >> 4;
  const int rowBase = blockIdx.y * 128;
  const int colBase = blockIdx.x * 128;
  float acc[8][8];
#pragma unroll
  for (int i = 0; i < 8; ++i)
#pragma unroll
    for (int j = 0; j < 8; ++j) acc[i][j] = 0.f;
  const int lr = tid >> 3;
  const int lc = (tid & 7) << 2;
  for (int kk = 0; kk < DD; kk += 32) {
#pragma unroll
    for (int r = 0; r < 4; ++r) {
      int row = lr + r * 32;
      float4 av = *(const float4*)(A + (size_t)(rowBase + row) * DD + kk + lc);
      float4 bv = *(const float4*)(B + (size_t)(colBase + row) * DD + kk + lc);
      As[lc + 0][row] = av.x; As[lc + 1][row] = av.y; As[lc + 2][row] = av.z; As[lc + 3][row] = av.w;
      Bs[lc + 0][row] = bv.x; Bs[lc + 1][row] = bv.y; Bs[lc + 2][row] = bv.z; Bs[lc + 3][row] = bv.w;
    }
    __syncthreads();
#pragma unroll 4
    for (int k = 0; k < 32; ++k) {
      float a[8], b[8];
      *(float4*)(a + 0) = *(const float4*)(&As[k][ty * 8 + 0]);
      *(float4*)(a + 4) = *(const float4*)(&As[k][ty * 8 + 4]);
      *(float4*)(b + 0) = *(const float4*)(&Bs[k][tx * 8 + 0]);
      *(float4*)(b + 4) = *(const float4*)(&Bs[k][tx * 8 + 4]);
#pragma unroll
      for (int i = 0; i < 8; ++i)
#pragma unroll
        for (int j = 0; j < 8; ++j)
          acc[i][j] = fmaf(a[i], b[j], acc[i][j]);
    }
    __syncthreads();
  }
  double colpart[8];
#pragma unroll
  for (int j = 0; j < 8; ++j) colpart[j] = 0.0;
#pragma unroll
  for (int i = 0; i < 8; ++i) {
    double rp = 0.0;
#pragma unroll
    for (int j = 0; j < 8; ++j) {
      float e = __expf(2.f * acc[i][j] - 2.f);
      rp += (double)e;
      colpart[j] += (double)e;
    }
#pragma unroll
    for (int off = 8; off; off >>= 1) rp += __shfl_down(rp, off, 16);
    if (tx == 0) atomicAdd(&R[rowBase + ty * 8 + i], rp);
  }
#pragma unroll
  for (int j = 0; j < 8; ++j) colLds[ty][tx * 8 + j] = colpart[j];
  __syncthreads();
  if (tid < 128) {
    double s = 0.0;
#pragma unroll
    for (int t = 0; t < 16; ++t) s += colLds[t][tid];
    atomicAdd(&CP[colBase + tid], s);   // partition 0 only
  }
#pragma unroll
  for (int i = 0; i < 8; ++i)
#pragma unroll
    for (int j = 0; j < 8; ++j) {
      if (acc[i][j] >= CAND_T0) {
        int idx = atomicAdd(cnt, 1);
        if (idx < ncap)
          cand[idx] = ((u32)(rowBase + ty * 8 + i) << 13) | (u32)(colBase + tx * 8 + j);
      }
    }
}

// One wave per candidate: exact fp64 dot, fp64 score, orderable u64 key.
__global__ __launch_bounds__(256) void k_score(
    const float* __restrict__ A, const float* __restrict__ B,
    const double* __restrict__ R, const double* __restrict__ CP,
    const int* __restrict__ cnt, const u32* __restrict__ cand,
    u64* __restrict__ keys, int ncap) {
  int w = (int)((blockIdx.x * 256 + threadIdx.x) >> 6);
  int lane = threadIdx.x & 63;
  int n = *cnt; if (n > ncap) n = ncap;
  if (w >= n) return;
  u32 mn = cand[w];
  int m = (int)(mn >> 13), nn = (int)(mn & 8191u);
  const float* ar = A + (size_t)m * DD;
  const float* br = B + (size_t)nn * DD;
  double s = 0.0;
#pragma unroll
  for (int d = 0; d < DD; d += 64)
    s = fma((double)ar[d + lane], (double)br[d + lane], s);
#pragma unroll
  for (int off = 32; off; off >>= 1) s += __shfl_down(s, off);
  if (lane == 0) {
    double Cn = 0.0;
#pragma unroll
    for (int x = 0; x < 8; ++x) Cn += CP[(size_t)x * ND + nn];
    double sc = exp(4.0 * s - 4.0) / (R[m] * Cn);
    keys[w] = (u64)__double_as_longlong(sc);
  }
}

// (key desc, flat-idx asc) strict order; idx unique so no true ties.
__device__ __forceinline__ bool is_worse(u64 ka, u32 ma, u64 kb, u32 mb) {
  return (ka < kb) || (ka == kb && ma > mb);
}

// Single-block top-256: register/shuffle bitonic. Fast path n<=2048, with
// dynamic merge depth (np=1024 when n<=1024 -> skip one bitonic level).
// Legacy 4096 LDS bitonic fallback.
__global__ __launch_bounds__(1024) void k_sort(
    const int* __restrict__ cnt, const u32* __restrict__ cand,
    const u64* __restrict__ keys, float* __restrict__ out, int ncap) {
  __shared__ u64 sk[NPAD];
  __shared__ u32 sm[NPAD];
  const int tid = threadIdx.x;
  const int lane = tid & 63;
  const int wid = tid >> 6;
  int m = *cnt; if (m > ncap) m = ncap;

  if (m <= 2048) {
    const int NP = (m <= 1024) ? 1024 : 2048;
    const int base = wid * 128;
    const int i0 = base + lane * 2;

    // wave-local sort of each 128-segment (reg/shuffle, zero barriers).
    // Padding segments (>= NP) sort trivially and are never merged/read.
    u64 k0 = (i0 < m) ? keys[i0] : 0;
    u64 k1 = (i0 + 1 < m) ? keys[i0 + 1] : 0;
    u32 m0 = (i0 < m) ? cand[i0] : 0xFFFFFFFFu;
    u32 m1 = (i0 + 1 < m) ? cand[i0 + 1] : 0xFFFFFFFFu;
#pragma unroll
    for (int k = 2; k <= 128; k <<= 1) {
#pragma unroll
      for (int j = k >> 1; j >= 1; j >>= 1) {
        const bool bf = ((i0 & k) == 0);
        if (j == 1) {
          bool sw = bf ? is_worse(k0, m0, k1, m1) : is_worse(k1, m1, k0, m0);
          if (sw) { u64 tk = k0; k0 = k1; k1 = tk; u32 tm = m0; m0 = m1; m1 = tm; }
        } else {
          const int j2 = j >> 1;
          const bool keepb = (bf == ((lane & j2) == 0));
          u64 pk0 = __shfl_xor(k0, j2); u32 pm0 = __shfl_xor(m0, j2);
          u64 pk1 = __shfl_xor(k1, j2); u32 pm1 = __shfl_xor(m1, j2);
          if (keepb == is_worse(k0, m0, pk0, pm0)) { k0 = pk0; m0 = pm0; }
          if (keepb == is_worse(k1, m1, pk1, pm1)) { k1 = pk1; m1 = pm1; }
        }
      }
    }
    sk[i0] = k0; sk[i0 + 1] = k1; sm[i0] = m0; sm[i0 + 1] = m1;
    __syncthreads();

    for (int k = 256; k <= NP; k <<= 1) {
      for (int j = k >> 1; j >= 128; j >>= 1) {
        for (int i = tid; i < NP; i += 1024) {
          int l = i ^ j;
          if (l > i) {
            u64 ki = sk[i], kl = sk[l];
            u32 mi = sm[i], ml = sm[l];
            bool bf = ((i & k) == 0);
            bool swp = bf ? is_worse(ki, mi, kl, ml) : is_worse(kl, ml, ki, mi);
            if (swp) { sk[i] = kl; sk[l] = ki; sm[i] = ml; sm[l] = mi; }
          }
        }
        __syncthreads();
      }
      if (i0 < NP) {
        k0 = sk[i0]; k1 = sk[i0 + 1]; m0 = sm[i0]; m1 = sm[i0 + 1];
        const bool bf = ((base & k) == 0);
#pragma unroll
        for (int j = 64; j >= 2; j >>= 1) {
          const int j2 = j >> 1;
          const bool keepb = (bf == ((lane & j2) == 0));
          u64 pk0 = __shfl_xor(k0, j2); u32 pm0 = __shfl_xor(m0, j2);
          u64 pk1 = __shfl_xor(k1, j2); u32 pm1 = __shfl_xor(m1, j2);
          if (keepb == is_worse(k0, m0, pk0, pm0)) { k0 = pk0; m0 = pm0; }
          if (keepb == is_worse(k1, m1, pk1, pm1)) { k1 = pk1; m1 = pm1; }
        }
        {
          bool sw = bf ? is_worse(k0, m0, k1, m1) : is_worse(k1, m1, k0, m0);
          if (sw) { u64 tk = k0; k0 = k1; k1 = tk; u32 tm = m0; m0 = m1; m1 = tm; }
        }
      }
      __syncthreads();
      if (i0 < NP) { sk[i0] = k0; sk[i0 + 1] = k1; sm[i0] = m0; sm[i0 + 1] = m1; }
      __syncthreads();
    }
  } else {
    for (int i = tid; i < NPAD; i += 1024) { sk[i] = 0; sm[i] = 0xFFFFFFFFu; }
    __syncthreads();
    for (int i = tid; i < m; i += 1024) { sk[i] = keys[i]; sm[i] = cand[i]; }
    __syncthreads();
    for (unsigned k = 2; k <= (unsigned)NPAD; k <<= 1) {
      for (unsigned j = k >> 1; j > 0; j >>= 1) {
        for (unsigned i = tid; i < (unsigned)NPAD; i += 1024) {
          unsigned l = i ^ j;
          if (l > i) {
            u64 ki = sk[i], kl = sk[l];
            u32 mi = sm[i], ml = sm[l];
            bool dir = ((i & k) == 0);
            bool swp = dir ? is_worse(ki, mi, kl, ml) : is_worse(kl, ml, ki, mi);
            if (swp) { sk[i] = kl; sk[l] = ki; sm[i] = ml; sm[l] = mi; }
          }
        }
        __syncthreads();
      }
    }
  }

  for (int r = tid; r < KTOP; r += 1024) {
    u32 mn = sm[r];
    u64 kk = sk[r];
    out[r] = (float)(mn >> 13);
    out[KTOP + r] = (float)(mn & 8191u);
    out[2 * KTOP + r] = (float)__longlong_as_double((long long)kk);
  }
}

extern "C" void kernel_launch(void* const* d_in, const int* in_sizes, int n_in,
                              void* d_out, int out_size, void* d_ws, size_t ws_size,
                              hipStream_t stream) {
  (void)in_sizes; (void)n_in; (void)out_size;
  const float* A = (const float*)d_in[0];  // ref_feats [8192,256]
  const float* B = (const float*)d_in[1];  // src_feats [8192,256]
  float* out = (float*)d_out;
  char* ws = (char*)d_ws;
  double* R = (double*)(ws + OFF_R);
  double* CP = (double*)(ws + OFF_CP);
  int* cnt = (int*)(ws + OFF_CNT);
  u32* cand = (u32*)(ws + OFF_CAND);
  u64* keys = (u64*)(ws + OFF_KEYS);

  if (ws_size >= (size_t)WS_REQ) {
    u16* Ahp = (u16*)(ws + OFF_AH);
    u16* Alp = (u16*)(ws + OFF_AL);
    u16* Bhp = (u16*)(ws + OFF_BH);
    u16* Blp = (u16*)(ws + OFF_BL);
    hipLaunchKernelGGL(k_prep2, dim3(2048), dim3(256), 0, stream,
                       A, B, Ahp, Alp, Bhp, Blp, R, CP, cnt);
    hipLaunchKernelGGL(k_gemm_mfma, dim3(4096), dim3(256), 0, stream,
                       Ahp, Alp, Bhp, Blp, R, CP, cnt, cand, NCAP);
  } else {
    hipLaunchKernelGGL(k_init, dim3(288), dim3(256), 0, stream, R, CP, cnt);
    hipLaunchKernelGGL(k_gemm_f32, dim3(ND / 128, MD / 128), dim3(256), 0, stream,
                       A, B, R, CP, cnt, cand, NCAP);
  }

  hipLaunchKernelGGL(k_score, dim3(NCAP / 4), dim3(256), 0, stream,
                     A, B, R, CP, cnt, cand, keys, NCAP);
  hipLaunchKernelGGL(k_sort, dim3(1), dim3(1024), 0, stream,
                     cnt, cand, keys, out, NCAP);
}